// Round 1
// baseline (334.748 us; speedup 1.0000x reference)
//
#include <hip/hip_runtime.h>

#define HID 20
#define NLAY 7

// tanh and its first three derivatives, via one hardware exp.
__device__ __forceinline__ float tanh_derivs(float a, float& d1, float& d2, float& d3) {
    float e = __expf(2.0f * a);
    float s = 1.0f - __fdividef(2.0f, e + 1.0f);
    d1 = 1.0f - s * s;          // f'
    d2 = -2.0f * s * d1;        // f''
    d3 = -2.0f * (d1 * d1 + s * d2); // f'''
    return s;
}

__global__ void __launch_bounds__(256, 1)
pinn_kernel(const float* __restrict__ xs, const float* __restrict__ ys, const float* __restrict__ ts,
            const float* __restrict__ W_in, const float* __restrict__ b_in,
            const float* __restrict__ W_hid, const float* __restrict__ b_hid,
            const float* __restrict__ W_out, const float* __restrict__ b_out,
            const float* __restrict__ lam1p, const float* __restrict__ lam2p,
            float* __restrict__ out, int N)
{
    const int idx = blockIdx.x * blockDim.x + threadIdx.x;
    if (idx >= N) return;
    const float xv = xs[idx], yv = ys[idx], tv = ts[idx];
    const float l1 = lam1p[0], l2 = lam2p[0];

    float u, v, p, ux, uy, vx, vy, px, py, lx, ly;

    // ================= Phase A =================
    // jet comps: 0=val 1=gx 2=gy 3=hxx 4=hxy 5=hyy 6=Lx(=fxxx+fxyy) 7=Ly(=fxxy+fyyy)
    {
        float h[HID][8];
        #pragma unroll
        for (int j = 0; j < HID; ++j) {
            const float w0 = W_in[j], w1 = W_in[HID + j], w2 = W_in[2 * HID + j];
            const float a0 = fmaf(xv, w0, fmaf(yv, w1, fmaf(tv, w2, b_in[j])));
            float d1, d2, d3;
            const float s = tanh_derivs(a0, d1, d2, d3);
            const float g2 = w0 * w0 + w1 * w1;
            h[j][0] = s;
            h[j][1] = d1 * w0;
            h[j][2] = d1 * w1;
            h[j][3] = d2 * w0 * w0;
            h[j][4] = d2 * w0 * w1;
            h[j][5] = d2 * w1 * w1;
            h[j][6] = d3 * w0 * g2;
            h[j][7] = d3 * w1 * g2;
        }
        #pragma unroll 1
        for (int l = 0; l < NLAY; ++l) {
            const float* __restrict__ Wl = W_hid + l * HID * HID;
            const float* __restrict__ bl = b_hid + l * HID;
            float acc[HID][8];
            #pragma unroll
            for (int j = 0; j < HID; ++j) {
                acc[j][0] = bl[j];
                #pragma unroll
                for (int c = 1; c < 8; ++c) acc[j][c] = 0.0f;
            }
            #pragma unroll
            for (int i = 0; i < HID; ++i) {
                #pragma unroll
                for (int j = 0; j < HID; ++j) {
                    const float w = Wl[i * HID + j];
                    #pragma unroll
                    for (int c = 0; c < 8; ++c) acc[j][c] = fmaf(w, h[i][c], acc[j][c]);
                }
            }
            #pragma unroll
            for (int j = 0; j < HID; ++j) {
                float d1, d2, d3;
                const float s  = tanh_derivs(acc[j][0], d1, d2, d3);
                const float gx = acc[j][1], gy = acc[j][2];
                const float hxx = acc[j][3], hxy = acc[j][4], hyy = acc[j][5];
                const float g2 = gx * gx + gy * gy;
                h[j][0] = s;
                h[j][1] = d1 * gx;
                h[j][2] = d1 * gy;
                h[j][3] = fmaf(d2, gx * gx, d1 * hxx);
                h[j][4] = fmaf(d2, gx * gy, d1 * hxy);
                h[j][5] = fmaf(d2, gy * gy, d1 * hyy);
                h[j][6] = d3 * gx * g2 + d2 * (3.0f * gx * hxx + 2.0f * gy * hxy + gx * hyy) + d1 * acc[j][6];
                h[j][7] = d3 * gy * g2 + d2 * (3.0f * gy * hyy + 2.0f * gx * hxy + gy * hxx) + d1 * acc[j][7];
            }
        }
        // output layer: psi = col 0, p = col 1 (bias only affects values)
        float psi[8];
        #pragma unroll
        for (int c = 0; c < 8; ++c) psi[c] = 0.0f;
        float p0 = 0.0f, p1 = 0.0f, p2 = 0.0f;
        #pragma unroll
        for (int i = 0; i < HID; ++i) {
            const float w0 = W_out[2 * i], w1 = W_out[2 * i + 1];
            #pragma unroll
            for (int c = 0; c < 8; ++c) psi[c] = fmaf(w0, h[i][c], psi[c]);
            p0 = fmaf(w1, h[i][0], p0);
            p1 = fmaf(w1, h[i][1], p1);
            p2 = fmaf(w1, h[i][2], p2);
        }
        u  = psi[2];           // psi_y
        v  = -psi[1];          // -psi_x
        p  = p0 + b_out[1];
        ux = psi[4];           // u_x = psi_yx
        uy = psi[5];           // u_y = psi_yy
        vx = -psi[3];          // v_x = -psi_xx
        vy = -psi[4];          // v_y = -psi_xy
        px = p1; py = p2;
        lx = psi[6];           // psi_xxx + psi_xyy
        ly = psi[7];           // psi_xxy + psi_yyy
    }

    // ================= Phase B =================
    // jet comps: 0=val 1=gx 2=gy 3=gt 4=hxt 5=hyt
    float ut, vt;
    {
        float h[HID][6];
        #pragma unroll
        for (int j = 0; j < HID; ++j) {
            const float w0 = W_in[j], w1 = W_in[HID + j], w2 = W_in[2 * HID + j];
            const float a0 = fmaf(xv, w0, fmaf(yv, w1, fmaf(tv, w2, b_in[j])));
            float d1, d2, d3;
            const float s = tanh_derivs(a0, d1, d2, d3);
            h[j][0] = s;
            h[j][1] = d1 * w0;
            h[j][2] = d1 * w1;
            h[j][3] = d1 * w2;
            h[j][4] = d2 * w0 * w2;
            h[j][5] = d2 * w1 * w2;
        }
        #pragma unroll 1
        for (int l = 0; l < NLAY; ++l) {
            const float* __restrict__ Wl = W_hid + l * HID * HID;
            const float* __restrict__ bl = b_hid + l * HID;
            float acc[HID][6];
            #pragma unroll
            for (int j = 0; j < HID; ++j) {
                acc[j][0] = bl[j];
                #pragma unroll
                for (int c = 1; c < 6; ++c) acc[j][c] = 0.0f;
            }
            #pragma unroll
            for (int i = 0; i < HID; ++i) {
                #pragma unroll
                for (int j = 0; j < HID; ++j) {
                    const float w = Wl[i * HID + j];
                    #pragma unroll
                    for (int c = 0; c < 6; ++c) acc[j][c] = fmaf(w, h[i][c], acc[j][c]);
                }
            }
            #pragma unroll
            for (int j = 0; j < HID; ++j) {
                float d1, d2, d3;
                const float s  = tanh_derivs(acc[j][0], d1, d2, d3);
                const float gx = acc[j][1], gy = acc[j][2], gt = acc[j][3];
                h[j][0] = s;
                h[j][1] = d1 * gx;
                h[j][2] = d1 * gy;
                h[j][3] = d1 * gt;
                h[j][4] = fmaf(d2, gx * gt, d1 * acc[j][4]);
                h[j][5] = fmaf(d2, gy * gt, d1 * acc[j][5]);
            }
        }
        float pxt = 0.0f, pyt = 0.0f;
        #pragma unroll
        for (int i = 0; i < HID; ++i) {
            const float w0 = W_out[2 * i];
            pxt = fmaf(w0, h[i][4], pxt);
            pyt = fmaf(w0, h[i][5], pyt);
        }
        ut = pyt;      // u_t = psi_yt
        vt = -pxt;     // v_t = -psi_xt
    }

    const float fu = ut + l1 * (u * ux + v * uy) + px - l2 * ly;
    const float fv = vt + l1 * (u * vx + v * vy) + py + l2 * lx;

    out[idx]         = u;
    out[N + idx]     = v;
    out[2 * N + idx] = p;
    out[3 * N + idx] = fu;
    out[4 * N + idx] = fv;
}

extern "C" void kernel_launch(void* const* d_in, const int* in_sizes, int n_in,
                              void* d_out, int out_size, void* d_ws, size_t ws_size,
                              hipStream_t stream) {
    const float* xs    = (const float*)d_in[0];
    const float* ys    = (const float*)d_in[1];
    const float* ts    = (const float*)d_in[2];
    const float* W_in  = (const float*)d_in[3];
    const float* b_in  = (const float*)d_in[4];
    const float* W_hid = (const float*)d_in[5];
    const float* b_hid = (const float*)d_in[6];
    const float* W_out = (const float*)d_in[7];
    const float* b_out = (const float*)d_in[8];
    const float* lam1  = (const float*)d_in[9];
    const float* lam2  = (const float*)d_in[10];
    float* out = (float*)d_out;

    const int N = in_sizes[0];
    const int block = 256;
    const int grid = (N + block - 1) / block;
    pinn_kernel<<<grid, block, 0, stream>>>(xs, ys, ts, W_in, b_in, W_hid, b_hid,
                                            W_out, b_out, lam1, lam2, out, N);
}